// Round 1
// baseline (119.647 us; speedup 1.0000x reference)
//
#include <hip/hip_runtime.h>
#include <math.h>

#define NMAX 1536
#define HID  16
#define BLK  256

// Weight bank layout (per spin-combo): [0:16) W1, [16:32) b1, [32:288) W2,
// [288:304) b2, [304:320) W3, [320] b3.  Stride padded to 324 floats so that
// (base + 32 floats) stays 16-byte aligned for float4 row reads of W2.
#define WSTRIDE 324

__device__ __forceinline__ float fast_tanh(float x) {
    float ax = fabsf(x);
    float t  = __expf(-2.0f * ax);                       // in (0,1]
    float r  = (1.0f - t) * __builtin_amdgcn_rcpf(1.0f + t);
    return copysignf(r, x);
}

extern "C" __global__ __launch_bounds__(BLK)
void pair_backflow_kernel(
    const float* __restrict__ x,   const float* __restrict__ cell,
    const float* __restrict__ Wp1, const float* __restrict__ bp1,
    const float* __restrict__ Wp2, const float* __restrict__ bp2,
    const float* __restrict__ Wp3, const float* __restrict__ bp3,
    const float* __restrict__ Wa1, const float* __restrict__ ba1,
    const float* __restrict__ Wa2, const float* __restrict__ ba2,
    const float* __restrict__ Wa3, const float* __restrict__ ba3,
    const int* __restrict__ n_up_ptr,
    float* __restrict__ out, int n)
{
    __shared__ __align__(16) float sW[2][WSTRIDE];
    __shared__ float sfrac[NMAX * 3];
    __shared__ float sred[BLK / 64][3];

    const int tid = threadIdx.x;
    const int j   = blockIdx.x;

    // ---- stage MLP weights into LDS (bank 0 = parallel spin, 1 = anti) ----
    if (tid < HID) {
        sW[0][tid]        = Wp1[tid];
        sW[0][16 + tid]   = bp1[tid];
        sW[0][288 + tid]  = bp2[tid];
        sW[0][304 + tid]  = Wp3[tid];
        sW[1][tid]        = Wa1[tid];
        sW[1][16 + tid]   = ba1[tid];
        sW[1][288 + tid]  = ba2[tid];
        sW[1][304 + tid]  = Wa3[tid];
    }
    {
        // 256 threads copy the two 256-entry W2 matrices
        sW[0][32 + tid] = Wp2[tid];
        sW[1][32 + tid] = Wa2[tid];
    }
    if (tid == 0) { sW[0][320] = bp3[0]; sW[1][320] = ba3[0]; }

    // ---- uniform per-thread: inv(cell), rs (scalar-register math) ----
    const float m00 = cell[0], m01 = cell[1], m02 = cell[2];
    const float m10 = cell[3], m11 = cell[4], m12 = cell[5];
    const float m20 = cell[6], m21 = cell[7], m22 = cell[8];
    const float det = m00 * (m11 * m22 - m12 * m21)
                    - m01 * (m10 * m22 - m12 * m20)
                    + m02 * (m10 * m21 - m11 * m20);
    const float id  = 1.0f / det;
    const float i00 = (m11 * m22 - m12 * m21) * id;
    const float i01 = (m02 * m21 - m01 * m22) * id;
    const float i02 = (m01 * m12 - m02 * m11) * id;
    const float i10 = (m12 * m20 - m10 * m22) * id;
    const float i11 = (m00 * m22 - m02 * m20) * id;
    const float i12 = (m02 * m10 - m00 * m12) * id;
    const float i20 = (m10 * m21 - m11 * m20) * id;
    const float i21 = (m01 * m20 - m00 * m21) * id;
    const float i22 = (m00 * m11 - m01 * m10) * id;

    const float PI  = 3.14159265358979323846f;
    const float IPI = 0.31830988618379067154f;
    const float vol_pp = fabsf(det) / (float)n;
    const float inv_rs = cbrtf(4.0f * PI / (3.0f * vol_pp)); // = 1/rs

    // ---- stage frac = x @ inv(cell) for ALL electrons into LDS ----
    for (int i = tid; i < n; i += BLK) {
        float x0 = x[i * 3 + 0], x1 = x[i * 3 + 1], x2 = x[i * 3 + 2];
        sfrac[i * 3 + 0] = x0 * i00 + x1 * i10 + x2 * i20;
        sfrac[i * 3 + 1] = x0 * i01 + x1 * i11 + x2 * i21;
        sfrac[i * 3 + 2] = x0 * i02 + x1 * i12 + x2 * i22;
    }
    __syncthreads();

    const int  n_up = *n_up_ptr;
    const bool j_up = (j < n_up);
    const float fj0 = sfrac[j * 3 + 0];
    const float fj1 = sfrac[j * 3 + 1];
    const float fj2 = sfrac[j * 3 + 2];

    float acc0 = 0.0f, acc1 = 0.0f, acc2 = 0.0f; // dr[j] partial

    for (int i = tid; i < n; i += BLK) {
        // periodic half-sinusoid displacement, pair (i, j): frac_i - frac_j
        float d0 = sfrac[i * 3 + 0] - fj0;
        float d1 = sfrac[i * 3 + 1] - fj1;
        float d2 = sfrac[i * 3 + 2] - fj2;
        float s0 = __sinf(PI * d0);
        float s1 = __sinf(PI * d1);
        float s2 = __sinf(PI * d2);
        float h0 = (s0 * m00 + s1 * m10 + s2 * m20) * IPI;
        float h1 = (s0 * m01 + s1 * m11 + s2 * m21) * IPI;
        float h2 = (s0 * m02 + s1 * m12 + s2 * m22) * IPI;
        float dist = sqrtf(h0 * h0 + h1 * h1 + h2 * h2);
        float sin_feat = dist * inv_rs;

        // spin-combo weight bank (wave-uniform: i-range and j are uniform)
        const bool  same = ((i < n_up) == j_up);
        const float* w   = sW[same ? 0 : 1];

        // layer 1: (1 -> 16)
        float g[HID];
#pragma unroll
        for (int l = 0; l < HID; ++l)
            g[l] = fast_tanh(fmaf(sin_feat, w[l], w[16 + l]));

        // layer 2: (16 -> 16), W2 rows broadcast from LDS as float4
        float t[HID];
#pragma unroll
        for (int l = 0; l < HID; ++l) t[l] = w[288 + l];
#pragma unroll
        for (int m = 0; m < HID; ++m) {
            float hm = g[m];
            const float4* row = (const float4*)(w + 32 + m * HID);
            float4 r0 = row[0], r1 = row[1], r2 = row[2], r3 = row[3];
            t[0]  = fmaf(hm, r0.x, t[0]);  t[1]  = fmaf(hm, r0.y, t[1]);
            t[2]  = fmaf(hm, r0.z, t[2]);  t[3]  = fmaf(hm, r0.w, t[3]);
            t[4]  = fmaf(hm, r1.x, t[4]);  t[5]  = fmaf(hm, r1.y, t[5]);
            t[6]  = fmaf(hm, r1.z, t[6]);  t[7]  = fmaf(hm, r1.w, t[7]);
            t[8]  = fmaf(hm, r2.x, t[8]);  t[9]  = fmaf(hm, r2.y, t[9]);
            t[10] = fmaf(hm, r2.z, t[10]); t[11] = fmaf(hm, r2.w, t[11]);
            t[12] = fmaf(hm, r3.x, t[12]); t[13] = fmaf(hm, r3.y, t[13]);
            t[14] = fmaf(hm, r3.z, t[14]); t[15] = fmaf(hm, r3.w, t[15]);
        }

        // layer 3: (16 -> 1)
        float eta = w[320];
#pragma unroll
        for (int l = 0; l < HID; ++l)
            eta = fmaf(fast_tanh(t[l]), w[304 + l], eta);

        // diagonal mask (same-spin block already handles spin masking)
        eta = (i == j) ? 0.0f : eta;

        // dr[j] -= eta[i,j] * d_hsin[i,j]
        acc0 = fmaf(-eta, h0, acc0);
        acc1 = fmaf(-eta, h1, acc1);
        acc2 = fmaf(-eta, h2, acc2);
    }

    // ---- block reduction: 64-lane shuffle, then cross-wave via LDS ----
#pragma unroll
    for (int off = 32; off > 0; off >>= 1) {
        acc0 += __shfl_xor(acc0, off);
        acc1 += __shfl_xor(acc1, off);
        acc2 += __shfl_xor(acc2, off);
    }
    const int lane = tid & 63;
    const int wid  = tid >> 6;
    if (lane == 0) {
        sred[wid][0] = acc0; sred[wid][1] = acc1; sred[wid][2] = acc2;
    }
    __syncthreads();
    if (tid < 3) {
        float dr = 0.0f;
#pragma unroll
        for (int wv = 0; wv < BLK / 64; ++wv) dr += sred[wv][tid];
        out[j * 3 + tid] = x[j * 3 + tid] + dr;
    }
}

extern "C" void kernel_launch(void* const* d_in, const int* in_sizes, int n_in,
                              void* d_out, int out_size, void* d_ws, size_t ws_size,
                              hipStream_t stream) {
    const float* x    = (const float*)d_in[0];
    const float* cell = (const float*)d_in[1];
    const float* Wp1  = (const float*)d_in[2];
    const float* bp1  = (const float*)d_in[3];
    const float* Wp2  = (const float*)d_in[4];
    const float* bp2  = (const float*)d_in[5];
    const float* Wp3  = (const float*)d_in[6];
    const float* bp3  = (const float*)d_in[7];
    const float* Wa1  = (const float*)d_in[8];
    const float* ba1  = (const float*)d_in[9];
    const float* Wa2  = (const float*)d_in[10];
    const float* ba2  = (const float*)d_in[11];
    const float* Wa3  = (const float*)d_in[12];
    const float* ba3  = (const float*)d_in[13];
    const int*   nup  = (const int*)d_in[14];
    float* out = (float*)d_out;

    const int n = in_sizes[0] / 3;

    pair_backflow_kernel<<<dim3(n), dim3(BLK), 0, stream>>>(
        x, cell, Wp1, bp1, Wp2, bp2, Wp3, bp3,
        Wa1, ba1, Wa2, ba2, Wa3, ba3, nup, out, n);
}

// Round 2
// 98.744 us; speedup vs baseline: 1.2117x; 1.2117x over previous
//
#include <hip/hip_runtime.h>
#include <math.h>

#define NMAX 1536
#define HID  16
#define BLK  256

__device__ __forceinline__ float fast_tanh(float x) {
    float ax = fabsf(x);
    float t  = __expf(-2.0f * ax);                       // in (0,1]
    float r  = (1.0f - t) * __builtin_amdgcn_rcpf(1.0f + t);
    return copysignf(r, x);
}

// full per-pair scalar MLP (only used in the tiny table-build kernel)
__device__ __forceinline__ float eta_mlp(float s,
    const float* __restrict__ W1, const float* __restrict__ b1,
    const float* __restrict__ W2, const float* __restrict__ b2,
    const float* __restrict__ W3, const float* __restrict__ b3)
{
    float g[HID];
#pragma unroll
    for (int l = 0; l < HID; ++l) g[l] = fast_tanh(fmaf(s, W1[l], b1[l]));
    float t[HID];
#pragma unroll
    for (int l = 0; l < HID; ++l) t[l] = b2[l];
#pragma unroll
    for (int m = 0; m < HID; ++m) {
        float gm = g[m];
#pragma unroll
        for (int l = 0; l < HID; ++l) t[l] = fmaf(gm, W2[m * HID + l], t[l]);
    }
    float eta = b3[0];
#pragma unroll
    for (int l = 0; l < HID; ++l) eta = fmaf(fast_tanh(t[l]), W3[l], eta);
    return eta;
}

// shared derived constants — MUST be identical arithmetic in both kernels
__device__ __forceinline__ void derive_consts(const float* __restrict__ cell,
                                              int n, float* inv_rs, float* smax_s)
{
    const float m00=cell[0],m01=cell[1],m02=cell[2];
    const float m10=cell[3],m11=cell[4],m12=cell[5];
    const float m20=cell[6],m21=cell[7],m22=cell[8];
    const float det = m00*(m11*m22-m12*m21)-m01*(m10*m22-m12*m20)+m02*(m10*m21-m11*m20);
    const float PI = 3.14159265358979323846f;
    const float vol_pp = fabsf(det) / (float)n;
    *inv_rs = cbrtf(4.0f * PI / (3.0f * vol_pp));
    // bound on |d_hsin|: sum of cell row norms / pi (|sin| <= 1 per component)
    const float r0 = sqrtf(m00*m00+m01*m01+m02*m02);
    const float r1 = sqrtf(m10*m10+m11*m11+m12*m12);
    const float r2 = sqrtf(m20*m20+m21*m21+m22*m22);
    *smax_s = (r0 + r1 + r2) * (1.0f / PI) * (*inv_rs) * 1.0005f;
}

extern "C" __global__ void build_eta_table(
    const float* __restrict__ cell,
    const float* __restrict__ Wp1, const float* __restrict__ bp1,
    const float* __restrict__ Wp2, const float* __restrict__ bp2,
    const float* __restrict__ Wp3, const float* __restrict__ bp3,
    const float* __restrict__ Wa1, const float* __restrict__ ba1,
    const float* __restrict__ Wa2, const float* __restrict__ ba2,
    const float* __restrict__ Wa3, const float* __restrict__ ba3,
    float2* __restrict__ tbl, int n, int tbl_n)
{
    const int t = blockIdx.x * blockDim.x + threadIdx.x;
    if (t >= 2 * tbl_n) return;
    const int bank = (t >= tbl_n) ? 1 : 0;
    const int idx  = bank ? (t - tbl_n) : t;

    float inv_rs, smax;
    derive_consts(cell, n, &inv_rs, &smax);
    const float ds = smax / (float)(tbl_n - 1);
    const float s  = idx * ds;

    float v0, v1;
    if (bank == 0) {
        v0 = eta_mlp(s,      Wp1, bp1, Wp2, bp2, Wp3, bp3);
        v1 = eta_mlp(s + ds, Wp1, bp1, Wp2, bp2, Wp3, bp3);
    } else {
        v0 = eta_mlp(s,      Wa1, ba1, Wa2, ba2, Wa3, ba3);
        v1 = eta_mlp(s + ds, Wa1, ba1, Wa2, ba2, Wa3, ba3);
    }
    tbl[t] = make_float2(v0, v1 - v0);   // (value, delta) for one-fma lerp
}

extern "C" __global__ __launch_bounds__(BLK)
void pair_backflow_main(
    const float* __restrict__ x, const float* __restrict__ cell,
    const int* __restrict__ n_up_ptr, const float2* __restrict__ tbl,
    float* __restrict__ out, int n, int tbl_n)
{
    __shared__ __align__(16) float4 sfrac[NMAX];   // padded: one ds_read_b128/pair
    __shared__ float sred[BLK / 64][3];

    const int tid = threadIdx.x;
    const int j   = blockIdx.x;

    // ---- wave-uniform: inv(cell), inv_rs, table scale, cell/pi rows ----
    const float m00 = cell[0], m01 = cell[1], m02 = cell[2];
    const float m10 = cell[3], m11 = cell[4], m12 = cell[5];
    const float m20 = cell[6], m21 = cell[7], m22 = cell[8];
    const float det = m00 * (m11 * m22 - m12 * m21)
                    - m01 * (m10 * m22 - m12 * m20)
                    + m02 * (m10 * m21 - m11 * m20);
    const float id  = 1.0f / det;
    const float i00 = (m11 * m22 - m12 * m21) * id;
    const float i01 = (m02 * m21 - m01 * m22) * id;
    const float i02 = (m01 * m12 - m02 * m11) * id;
    const float i10 = (m12 * m20 - m10 * m22) * id;
    const float i11 = (m00 * m22 - m02 * m20) * id;
    const float i12 = (m02 * m10 - m00 * m12) * id;
    const float i20 = (m10 * m21 - m11 * m20) * id;
    const float i21 = (m01 * m20 - m00 * m21) * id;
    const float i22 = (m00 * m11 - m01 * m10) * id;

    const float PI  = 3.14159265358979323846f;
    const float IPI = 0.31830988618379067154f;

    float inv_rs, smax;
    derive_consts(cell, n, &inv_rs, &smax);
    const float c_u  = inv_rs * (float)(tbl_n - 1) / smax;  // dist -> table coord
    const float umax = (float)(tbl_n - 1);

    // cell rows pre-scaled by 1/pi
    const float c00 = m00 * IPI, c01 = m01 * IPI, c02 = m02 * IPI;
    const float c10 = m10 * IPI, c11 = m11 * IPI, c12 = m12 * IPI;
    const float c20 = m20 * IPI, c21 = m21 * IPI, c22 = m22 * IPI;

    // ---- stage frac = x @ inv(cell) into LDS (float4-padded) ----
    for (int i = tid; i < n; i += BLK) {
        float x0 = x[i * 3 + 0], x1 = x[i * 3 + 1], x2 = x[i * 3 + 2];
        float4 f;
        f.x = x0 * i00 + x1 * i10 + x2 * i20;
        f.y = x0 * i01 + x1 * i11 + x2 * i21;
        f.z = x0 * i02 + x1 * i12 + x2 * i22;
        f.w = 0.0f;
        sfrac[i] = f;
    }
    __syncthreads();

    const int  n_up = *n_up_ptr;
    const bool j_up = (j < n_up);
    const float4 fj = sfrac[j];

    float acc0 = 0.0f, acc1 = 0.0f, acc2 = 0.0f;

    for (int i = tid; i < n; i += BLK) {
        float4 fi = sfrac[i];
        float s0 = __sinf(PI * (fi.x - fj.x));
        float s1 = __sinf(PI * (fi.y - fj.y));
        float s2 = __sinf(PI * (fi.z - fj.z));
        float h0 = s0 * c00 + s1 * c10 + s2 * c20;
        float h1 = s0 * c01 + s1 * c11 + s2 * c21;
        float h2 = s0 * c02 + s1 * c12 + s2 * c22;
        float dist = sqrtf(fmaf(h0, h0, fmaf(h1, h1, h2 * h2)));

        float u = fminf(dist * c_u, umax);
        int   idx = (int)u;
        float fr  = u - (float)idx;

        const bool same = ((i < n_up) == j_up);
        float2 e = tbl[(same ? 0 : tbl_n) + idx];
        float eta = fmaf(fr, e.y, e.x);
        eta = (i == j) ? 0.0f : eta;

        acc0 = fmaf(-eta, h0, acc0);
        acc1 = fmaf(-eta, h1, acc1);
        acc2 = fmaf(-eta, h2, acc2);
    }

    // ---- block reduction ----
#pragma unroll
    for (int off = 32; off > 0; off >>= 1) {
        acc0 += __shfl_xor(acc0, off);
        acc1 += __shfl_xor(acc1, off);
        acc2 += __shfl_xor(acc2, off);
    }
    const int lane = tid & 63;
    const int wid  = tid >> 6;
    if (lane == 0) {
        sred[wid][0] = acc0; sred[wid][1] = acc1; sred[wid][2] = acc2;
    }
    __syncthreads();
    if (tid < 3) {
        float dr = 0.0f;
#pragma unroll
        for (int wv = 0; wv < BLK / 64; ++wv) dr += sred[wv][tid];
        out[j * 3 + tid] = x[j * 3 + tid] + dr;
    }
}

extern "C" void kernel_launch(void* const* d_in, const int* in_sizes, int n_in,
                              void* d_out, int out_size, void* d_ws, size_t ws_size,
                              hipStream_t stream) {
    const float* x    = (const float*)d_in[0];
    const float* cell = (const float*)d_in[1];
    const float* Wp1  = (const float*)d_in[2];
    const float* bp1  = (const float*)d_in[3];
    const float* Wp2  = (const float*)d_in[4];
    const float* bp2  = (const float*)d_in[5];
    const float* Wp3  = (const float*)d_in[6];
    const float* bp3  = (const float*)d_in[7];
    const float* Wa1  = (const float*)d_in[8];
    const float* ba1  = (const float*)d_in[9];
    const float* Wa2  = (const float*)d_in[10];
    const float* ba2  = (const float*)d_in[11];
    const float* Wa3  = (const float*)d_in[12];
    const float* ba3  = (const float*)d_in[13];
    const int*   nup  = (const int*)d_in[14];
    float* out = (float*)d_out;

    const int n = in_sizes[0] / 3;

    // pick table size to fit workspace (float2 per entry, 2 banks)
    int tbl_n = 2048;
    if (ws_size >= (size_t)(2 * 4096) * sizeof(float2)) tbl_n = 4096;
    else if (ws_size < (size_t)(2 * 2048) * sizeof(float2)) tbl_n = 512;
    float2* tbl = (float2*)d_ws;

    const int bt = (2 * tbl_n + BLK - 1) / BLK;
    build_eta_table<<<dim3(bt), dim3(BLK), 0, stream>>>(
        cell, Wp1, bp1, Wp2, bp2, Wp3, bp3,
        Wa1, ba1, Wa2, ba2, Wa3, ba3, tbl, n, tbl_n);

    pair_backflow_main<<<dim3(n), dim3(BLK), 0, stream>>>(
        x, cell, nup, tbl, out, n, tbl_n);
}

// Round 3
// 97.720 us; speedup vs baseline: 1.2244x; 1.0105x over previous
//
#include <hip/hip_runtime.h>
#include <math.h>

#define HID   16
#define BLK   256
#define TBL_N 4096

__device__ __forceinline__ float fast_tanh(float x) {
    float ax = fabsf(x);
    float t  = __expf(-2.0f * ax);                       // in (0,1]
    float r  = (1.0f - t) * __builtin_amdgcn_rcpf(1.0f + t);
    return copysignf(r, x);
}

// full per-pair scalar MLP (only used in the tiny table-build kernel)
__device__ __forceinline__ float eta_mlp(float s,
    const float* __restrict__ W1, const float* __restrict__ b1,
    const float* __restrict__ W2, const float* __restrict__ b2,
    const float* __restrict__ W3, const float* __restrict__ b3)
{
    float g[HID];
#pragma unroll
    for (int l = 0; l < HID; ++l) g[l] = fast_tanh(fmaf(s, W1[l], b1[l]));
    float t[HID];
#pragma unroll
    for (int l = 0; l < HID; ++l) t[l] = b2[l];
#pragma unroll
    for (int m = 0; m < HID; ++m) {
        float gm = g[m];
#pragma unroll
        for (int l = 0; l < HID; ++l) t[l] = fmaf(gm, W2[m * HID + l], t[l]);
    }
    float eta = b3[0];
#pragma unroll
    for (int l = 0; l < HID; ++l) eta = fmaf(fast_tanh(t[l]), W3[l], eta);
    return eta;
}

// derived constants — identical arithmetic in both kernels
__device__ __forceinline__ void derive_consts(const float* __restrict__ cell,
                                              int n, float* inv_rs, float* smax_s)
{
    const float m00=cell[0],m01=cell[1],m02=cell[2];
    const float m10=cell[3],m11=cell[4],m12=cell[5];
    const float m20=cell[6],m21=cell[7],m22=cell[8];
    const float det = m00*(m11*m22-m12*m21)-m01*(m10*m22-m12*m20)+m02*(m10*m21-m11*m20);
    const float PI = 3.14159265358979323846f;
    const float vol_pp = fabsf(det) / (float)n;
    *inv_rs = cbrtf(4.0f * PI / (3.0f * vol_pp));
    const float r0 = sqrtf(m00*m00+m01*m01+m02*m02);
    const float r1 = sqrtf(m10*m10+m11*m11+m12*m12);
    const float r2 = sqrtf(m20*m20+m21*m21+m22*m22);
    *smax_s = (r0 + r1 + r2) * (1.0f / PI) * (*inv_rs) * 1.0005f;
}

// builds: (a) eta lookup tables for both spin banks, (b) frac = x @ inv(cell)
extern "C" __global__ void build_tables(
    const float* __restrict__ x, const float* __restrict__ cell,
    const float* __restrict__ Wp1, const float* __restrict__ bp1,
    const float* __restrict__ Wp2, const float* __restrict__ bp2,
    const float* __restrict__ Wp3, const float* __restrict__ bp3,
    const float* __restrict__ Wa1, const float* __restrict__ ba1,
    const float* __restrict__ Wa2, const float* __restrict__ ba2,
    const float* __restrict__ Wa3, const float* __restrict__ ba3,
    float2* __restrict__ tbl, float4* __restrict__ frac, int n)
{
    const int t = blockIdx.x * blockDim.x + threadIdx.x;

    if (t < 2 * TBL_N) {
        const int bank = (t >= TBL_N) ? 1 : 0;
        const int idx  = bank ? (t - TBL_N) : t;

        float inv_rs, smax;
        derive_consts(cell, n, &inv_rs, &smax);
        const float ds = smax / (float)(TBL_N - 1);
        const float s  = idx * ds;

        float v0, v1;
        if (bank == 0) {
            v0 = eta_mlp(s,      Wp1, bp1, Wp2, bp2, Wp3, bp3);
            v1 = eta_mlp(s + ds, Wp1, bp1, Wp2, bp2, Wp3, bp3);
        } else {
            v0 = eta_mlp(s,      Wa1, ba1, Wa2, ba2, Wa3, ba3);
            v1 = eta_mlp(s + ds, Wa1, ba1, Wa2, ba2, Wa3, ba3);
        }
        tbl[t] = make_float2(v0, v1 - v0);   // (value, delta) for one-fma lerp
        return;
    }

    const int i = t - 2 * TBL_N;
    if (i < n) {
        const float m00=cell[0],m01=cell[1],m02=cell[2];
        const float m10=cell[3],m11=cell[4],m12=cell[5];
        const float m20=cell[6],m21=cell[7],m22=cell[8];
        const float det = m00*(m11*m22-m12*m21)-m01*(m10*m22-m12*m20)+m02*(m10*m21-m11*m20);
        const float id  = 1.0f / det;
        const float i00=(m11*m22-m12*m21)*id, i01=(m02*m21-m01*m22)*id, i02=(m01*m12-m02*m11)*id;
        const float i10=(m12*m20-m10*m22)*id, i11=(m00*m22-m02*m20)*id, i12=(m02*m10-m00*m12)*id;
        const float i20=(m10*m21-m11*m20)*id, i21=(m01*m20-m00*m21)*id, i22=(m00*m11-m01*m10)*id;
        float x0 = x[i*3+0], x1 = x[i*3+1], x2 = x[i*3+2];
        float4 f;
        f.x = x0*i00 + x1*i10 + x2*i20;
        f.y = x0*i01 + x1*i11 + x2*i21;
        f.z = x0*i02 + x1*i12 + x2*i22;
        f.w = 0.0f;
        frac[i] = f;
    }
}

extern "C" __global__ __launch_bounds__(BLK)
void pair_backflow_main(
    const float* __restrict__ x, const float* __restrict__ cell,
    const int* __restrict__ n_up_ptr,
    const float2* __restrict__ tbl, const float4* __restrict__ frac,
    float* __restrict__ out, int n)
{
    __shared__ float sred[BLK / 64][3];

    const int tid = threadIdx.x;
    const int j   = blockIdx.x;

    // wave-uniform constants
    const float m00=cell[0],m01=cell[1],m02=cell[2];
    const float m10=cell[3],m11=cell[4],m12=cell[5];
    const float m20=cell[6],m21=cell[7],m22=cell[8];
    const float IPI = 0.31830988618379067154f;
    const float c00=m00*IPI, c01=m01*IPI, c02=m02*IPI;
    const float c10=m10*IPI, c11=m11*IPI, c12=m12*IPI;
    const float c20=m20*IPI, c21=m21*IPI, c22=m22*IPI;

    float inv_rs, smax;
    derive_consts(cell, n, &inv_rs, &smax);
    const float c_u  = inv_rs * (float)(TBL_N - 1) / smax;  // dist -> table coord
    const float umax = (float)(TBL_N - 1);

    const int  n_up = *n_up_ptr;
    const bool j_up = (j < n_up);
    const float4 fj = frac[j];

    float acc0 = 0.0f, acc1 = 0.0f, acc2 = 0.0f;

    for (int i = tid; i < n; i += BLK) {
        float4 fi = frac[i];
        // sin(pi*d) via raw HW sin (revolutions): no range reduction, |arg|<0.5
        float s0 = __builtin_amdgcn_sinf(0.5f * (fi.x - fj.x));
        float s1 = __builtin_amdgcn_sinf(0.5f * (fi.y - fj.y));
        float s2 = __builtin_amdgcn_sinf(0.5f * (fi.z - fj.z));
        float h0 = fmaf(s0, c00, fmaf(s1, c10, s2 * c20));
        float h1 = fmaf(s0, c01, fmaf(s1, c11, s2 * c21));
        float h2 = fmaf(s0, c02, fmaf(s1, c12, s2 * c22));
        float dist = sqrtf(fmaf(h0, h0, fmaf(h1, h1, h2 * h2)));

        float u   = fminf(dist * c_u, umax);
        int   idx = (int)u;
        float fr  = u - (float)idx;

        const bool same = ((i < n_up) == j_up);
        float2 e = tbl[(same ? 0 : TBL_N) + idx];
        float eta = fmaf(fr, e.y, e.x);
        eta = (i == j) ? 0.0f : eta;

        acc0 = fmaf(-eta, h0, acc0);
        acc1 = fmaf(-eta, h1, acc1);
        acc2 = fmaf(-eta, h2, acc2);
    }

    // block reduction: 64-lane butterfly, then cross-wave via LDS
#pragma unroll
    for (int off = 32; off > 0; off >>= 1) {
        acc0 += __shfl_xor(acc0, off);
        acc1 += __shfl_xor(acc1, off);
        acc2 += __shfl_xor(acc2, off);
    }
    const int lane = tid & 63;
    const int wid  = tid >> 6;
    if (lane == 0) {
        sred[wid][0] = acc0; sred[wid][1] = acc1; sred[wid][2] = acc2;
    }
    __syncthreads();
    if (tid < 3) {
        float dr = 0.0f;
#pragma unroll
        for (int wv = 0; wv < BLK / 64; ++wv) dr += sred[wv][tid];
        out[j * 3 + tid] = x[j * 3 + tid] + dr;
    }
}

extern "C" void kernel_launch(void* const* d_in, const int* in_sizes, int n_in,
                              void* d_out, int out_size, void* d_ws, size_t ws_size,
                              hipStream_t stream) {
    const float* x    = (const float*)d_in[0];
    const float* cell = (const float*)d_in[1];
    const float* Wp1  = (const float*)d_in[2];
    const float* bp1  = (const float*)d_in[3];
    const float* Wp2  = (const float*)d_in[4];
    const float* bp2  = (const float*)d_in[5];
    const float* Wp3  = (const float*)d_in[6];
    const float* bp3  = (const float*)d_in[7];
    const float* Wa1  = (const float*)d_in[8];
    const float* ba1  = (const float*)d_in[9];
    const float* Wa2  = (const float*)d_in[10];
    const float* ba2  = (const float*)d_in[11];
    const float* Wa3  = (const float*)d_in[12];
    const float* ba3  = (const float*)d_in[13];
    const int*   nup  = (const int*)d_in[14];
    float* out = (float*)d_out;

    const int n = in_sizes[0] / 3;

    // ws layout: [0, 2*TBL_N float2) eta tables | then n float4 frac
    float2* tbl  = (float2*)d_ws;
    float4* frac = (float4*)((char*)d_ws + (size_t)(2 * TBL_N) * sizeof(float2));

    const int work = 2 * TBL_N + n;
    build_tables<<<dim3((work + BLK - 1) / BLK), dim3(BLK), 0, stream>>>(
        x, cell, Wp1, bp1, Wp2, bp2, Wp3, bp3,
        Wa1, ba1, Wa2, ba2, Wa3, ba3, tbl, frac, n);

    pair_backflow_main<<<dim3(n), dim3(BLK), 0, stream>>>(
        x, cell, nup, tbl, frac, out, n);
}